// Round 1
// baseline (520.073 us; speedup 1.0000x reference)
//
#include <hip/hip_runtime.h>
#include <hip/hip_bf16.h>

typedef __bf16 bf16;
typedef bf16 bf16x4 __attribute__((ext_vector_type(4)));
typedef bf16 bf16x8 __attribute__((ext_vector_type(8)));
typedef float f32x4 __attribute__((ext_vector_type(4)));

#define MFMA16(A,B,C) __builtin_amdgcn_mfma_f32_16x16x32_bf16(A,B,C,0,0,0)

__device__ __forceinline__ void gld_lds16(const void* g, void* l) {
  __builtin_amdgcn_global_load_lds(
      (const __attribute__((address_space(1))) void*)g,
      (__attribute__((address_space(3))) void*)l, 16, 0, 0);
}

// ---------------- fp32 -> bf16 cast ----------------
__global__ void cast_kernel(const float* __restrict__ in, bf16* __restrict__ out, int n4) {
  int i = blockIdx.x * blockDim.x + threadIdx.x;
  if (i >= n4) return;
  float4 v = ((const float4*)in)[i];
  bf16x4 o;
  o[0] = (bf16)v.x; o[1] = (bf16)v.y; o[2] = (bf16)v.z; o[3] = (bf16)v.w;
  *(bf16x4*)(out + (size_t)i * 4) = o;
}

// ---------------- GEMM  C = A * B^T  (+bias)*scale ----------------
// A: MxK bf16 row-major, Bm: NxK bf16 row-major (i.e. B-transposed storage).
// OUT_MODE 0: bf16 [M][N];  1: bf16 V^T layout vt[(b*1024+e)][2048]+s;  2: f32 [M][N]
template<int OUT_MODE>
__global__ __launch_bounds__(256) void gemm_bt_kernel(
    const bf16* __restrict__ A, const bf16* __restrict__ Bm,
    const float* __restrict__ bias, void* __restrict__ Cout,
    int M, int N, int K, float scale)
{
  __shared__ bf16 sA[2][128 * 32];
  __shared__ bf16 sB[2][128 * 32];
  const int t = threadIdx.x;
  const int lane = t & 63, w = t >> 6;
  const int wr = w >> 1, wc = w & 1;
  const int g = lane >> 4, c = lane & 15;
  const int bm = blockIdx.y, bn = blockIdx.x;

  f32x4 acc[4][4] = {};

  const int NT = K >> 5;
  const int arow = t >> 2;
  const int acol = (t & 3) * 8;
  const bf16* aBase = A + (size_t)(bm * 128) * K;
  const bf16* bBase = Bm + (size_t)(bn * 128) * K;

  auto stage = [&](int buf, int kt) {
    const int k0 = kt * 32;
#pragma unroll
    for (int i = 0; i < 2; ++i) {
      const int row = arow + i * 64;
      gld_lds16(aBase + (size_t)row * K + k0 + acol, &sA[buf][(i * 256 + t) * 8]);
      gld_lds16(bBase + (size_t)row * K + k0 + acol, &sB[buf][(i * 256 + t) * 8]);
    }
  };

  stage(0, 0);
  __syncthreads();
  int cur = 0;
  for (int kt = 0; kt < NT; ++kt) {
    if (kt + 1 < NT) stage(cur ^ 1, kt + 1);
    bf16x8 af[4], bfr[4];
#pragma unroll
    for (int m = 0; m < 4; ++m)
      af[m] = *(const bf16x8*)&sA[cur][(wr * 64 + m * 16 + c) * 32 + g * 8];
#pragma unroll
    for (int n = 0; n < 4; ++n)
      bfr[n] = *(const bf16x8*)&sB[cur][(wc * 64 + n * 16 + c) * 32 + g * 8];
#pragma unroll
    for (int m = 0; m < 4; ++m)
#pragma unroll
      for (int n = 0; n < 4; ++n)
        acc[m][n] = MFMA16(af[m], bfr[n], acc[m][n]);
    __syncthreads();
    cur ^= 1;
  }

#pragma unroll
  for (int n = 0; n < 4; ++n) {
    const int col = bn * 128 + wc * 64 + n * 16 + c;
    const float bv = bias[col];
#pragma unroll
    for (int m = 0; m < 4; ++m) {
#pragma unroll
      for (int r = 0; r < 4; ++r) {
        const int row = bm * 128 + wr * 64 + m * 16 + g * 4 + r;
        const float val = (acc[m][n][r] + bv) * scale;
        if (OUT_MODE == 0) {
          ((bf16*)Cout)[(size_t)row * N + col] = (bf16)val;
        } else if (OUT_MODE == 1) {
          const int bb = row >> 11, s = row & 2047;
          ((bf16*)Cout)[((size_t)(bb * 1024 + col)) * 2048 + s] = (bf16)val;
        } else {
          ((float*)Cout)[(size_t)row * N + col] = val;
        }
      }
    }
  }
}

// ---------------- flash attention ----------------
// Qp,Kp: [B*S][D] bf16 (Q pre-scaled by 1/8). Vt: [(b*H+h)*DK+dk][S] bf16.
// Out: [B*S][D] bf16.  Block: 256 thr (4 waves), 128 q-rows, KBLK=64.
__global__ __launch_bounds__(256) void attn_kernel(
    const bf16* __restrict__ Qp, const bf16* __restrict__ Kp, const bf16* __restrict__ Vt,
    const int* __restrict__ mask, bf16* __restrict__ Out)
{
  __shared__ bf16 sK[2][64 * 64];
  __shared__ bf16 sV[2][64 * 64];
  __shared__ bf16 sP[4][32 * 72];   // per-wave P, padded stride 72

  const int bh = blockIdx.x;
  const int b = bh >> 4, h = bh & 15;
  const int t = threadIdx.x, lane = t & 63, w = t >> 6;
  const int g = lane >> 4, c = lane & 15;
  const int q0 = blockIdx.y * 128 + w * 32;

  const char* kBase = (const char*)(Kp + (size_t)(b * 2048) * 1024 + h * 64);
  const char* vBase = (const char*)(Vt + (size_t)(bh * 64) * 2048);

  auto stageKV = [&](int buf, int kt) {
#pragma unroll
    for (int i = 0; i < 2; ++i) {
      const int idx = i * 256 + t;
      const int row = idx >> 3;                       // 0..63
      const int cb = ((t & 7) * 16) ^ ((row & 7) << 4);  // swizzled source byte
      gld_lds16(kBase + (size_t)(kt * 64 + row) * 2048 + cb, (char*)sK[buf] + idx * 16);
      gld_lds16(vBase + (size_t)row * 4096 + kt * 128 + cb, (char*)sV[buf] + idx * 16);
    }
  };

  // Q fragments (A-layout), held in registers
  bf16x8 qf[2][2];
#pragma unroll
  for (int m = 0; m < 2; ++m)
#pragma unroll
    for (int ks = 0; ks < 2; ++ks)
      qf[m][ks] = *(const bf16x8*)&Qp[(size_t)(b * 2048 + q0 + m * 16 + c) * 1024 + h * 64 + ks * 32 + g * 8];

  float mrun[2][4], lrun[2][4];
  f32x4 aco[2][4] = {};
#pragma unroll
  for (int m = 0; m < 2; ++m)
#pragma unroll
    for (int r = 0; r < 4; ++r) { mrun[m][r] = -1e30f; lrun[m][r] = 0.f; }

  const int* mrow = mask + b * 2048;

  stageKV(0, 0);
  __syncthreads();
  int cur = 0;
  for (int kt = 0; kt < 32; ++kt) {
    if (kt + 1 < 32) stageKV(cur ^ 1, kt + 1);

    // ---- S^ = Q K^T ----
    f32x4 s[2][4] = {};
#pragma unroll
    for (int ks = 0; ks < 2; ++ks) {
      bf16x8 kf[4];
#pragma unroll
      for (int n = 0; n < 4; ++n) {
        const int row = n * 16 + c;
        const int byt = (row * 128 + ks * 64 + g * 16) ^ ((row & 7) << 4);
        kf[n] = *(const bf16x8*)((const char*)sK[cur] + byt);
      }
#pragma unroll
      for (int m = 0; m < 2; ++m)
#pragma unroll
        for (int n = 0; n < 4; ++n)
          s[m][n] = MFMA16(qf[m][ks], kf[n], s[m][n]);
    }

    // ---- mask ----
    float madd[4];
#pragma unroll
    for (int n = 0; n < 4; ++n)
      madd[n] = (mrow[kt * 64 + n * 16 + c] == 0) ? -1e9f : 0.0f;
#pragma unroll
    for (int m = 0; m < 2; ++m)
#pragma unroll
      for (int n = 0; n < 4; ++n)
#pragma unroll
        for (int r = 0; r < 4; ++r) s[m][n][r] += madd[n];

    // ---- online softmax (row = q = g*4+r within frag, cols spread over c,n) ----
#pragma unroll
    for (int m = 0; m < 2; ++m) {
#pragma unroll
      for (int r = 0; r < 4; ++r) {
        float tmax = fmaxf(fmaxf(s[m][0][r], s[m][1][r]), fmaxf(s[m][2][r], s[m][3][r]));
#pragma unroll
        for (int d = 8; d >= 1; d >>= 1) tmax = fmaxf(tmax, __shfl_xor(tmax, d, 64));
        const float mnew = fmaxf(mrun[m][r], tmax);
        const float sc = __expf(mrun[m][r] - mnew);
        mrun[m][r] = mnew;
        float rs = 0.f;
#pragma unroll
        for (int n = 0; n < 4; ++n) {
          float p = __expf(s[m][n][r] - mnew);
          s[m][n][r] = p;
          rs += p;
        }
#pragma unroll
        for (int d = 8; d >= 1; d >>= 1) rs += __shfl_xor(rs, d, 64);
        lrun[m][r] = lrun[m][r] * sc + rs;
#pragma unroll
        for (int n = 0; n < 4; ++n) aco[m][n][r] *= sc;
      }
    }

    // ---- P -> per-wave LDS (bf16, padded) ----
    bf16* pw = sP[w];
#pragma unroll
    for (int m = 0; m < 2; ++m)
#pragma unroll
      for (int n = 0; n < 4; ++n)
#pragma unroll
        for (int r = 0; r < 4; ++r)
          pw[(m * 16 + g * 4 + r) * 72 + n * 16 + c] = (bf16)s[m][n][r];

    // ---- O += P V  (Vt gives B^T-style reads) ----
#pragma unroll
    for (int ks = 0; ks < 2; ++ks) {
      bf16x8 pa[2], vb[4];
#pragma unroll
      for (int m = 0; m < 2; ++m)
        pa[m] = *(const bf16x8*)&pw[(m * 16 + c) * 72 + ks * 32 + g * 8];
#pragma unroll
      for (int n = 0; n < 4; ++n) {
        const int row = n * 16 + c;  // dk
        const int byt = (row * 128 + ks * 64 + g * 16) ^ ((row & 7) << 4);
        vb[n] = *(const bf16x8*)((const char*)sV[cur] + byt);
      }
#pragma unroll
      for (int m = 0; m < 2; ++m)
#pragma unroll
        for (int n = 0; n < 4; ++n)
          aco[m][n] = MFMA16(pa[m], vb[n], aco[m][n]);
    }

    __syncthreads();
    cur ^= 1;
  }

  // ---- epilogue ----
#pragma unroll
  for (int m = 0; m < 2; ++m) {
#pragma unroll
    for (int r = 0; r < 4; ++r) {
      const int q = q0 + m * 16 + g * 4 + r;
      const float inv = 1.0f / lrun[m][r];
#pragma unroll
      for (int n = 0; n < 4; ++n) {
        const int dk = n * 16 + c;
        Out[(size_t)(b * 2048 + q) * 1024 + h * 64 + dk] = (bf16)(aco[m][n][r] * inv);
      }
    }
  }
}

extern "C" void kernel_launch(void* const* d_in, const int* in_sizes, int n_in,
                              void* d_out, int out_size, void* d_ws, size_t ws_size,
                              hipStream_t stream) {
  const float* q  = (const float*)d_in[0];
  const float* k  = (const float*)d_in[1];
  const float* v  = (const float*)d_in[2];
  const int*  msk = (const int*)d_in[3];
  const float* wq = (const float*)d_in[4];
  const float* bq = (const float*)d_in[5];
  const float* wk = (const float*)d_in[6];
  const float* bk = (const float*)d_in[7];
  const float* wv = (const float*)d_in[8];
  const float* bv = (const float*)d_in[9];
  const float* wo = (const float*)d_in[10];
  const float* bo = (const float*)d_in[11];

  bf16* ws = (bf16*)d_ws;
  const size_t NEL = 8192ull * 1024ull;  // 8M elements
  bf16* qx  = ws;
  bf16* kx  = ws + NEL;
  bf16* vx  = ws + 2 * NEL;
  bf16* wqb = ws + 3 * NEL;
  bf16* wkb = wqb + 1048576;
  bf16* wvb = wkb + 1048576;
  bf16* wob = wvb + 1048576;
  bf16* qp  = wob + 1048576;
  bf16* kp  = qp + NEL;
  bf16* vt  = kp + NEL;
  bf16* ao  = vx;  // vx dead after V projection

  cast_kernel<<<8192, 256, 0, stream>>>(q, qx, 2097152);
  cast_kernel<<<8192, 256, 0, stream>>>(k, kx, 2097152);
  cast_kernel<<<8192, 256, 0, stream>>>(v, vx, 2097152);
  cast_kernel<<<1024, 256, 0, stream>>>(wq, wqb, 262144);
  cast_kernel<<<1024, 256, 0, stream>>>(wk, wkb, 262144);
  cast_kernel<<<1024, 256, 0, stream>>>(wv, wvb, 262144);
  cast_kernel<<<1024, 256, 0, stream>>>(wo, wob, 262144);

  dim3 gg(8, 64);
  gemm_bt_kernel<0><<<gg, 256, 0, stream>>>(qx, wqb, bq, qp, 8192, 1024, 1024, 0.125f);
  gemm_bt_kernel<0><<<gg, 256, 0, stream>>>(kx, wkb, bk, kp, 8192, 1024, 1024, 1.0f);
  gemm_bt_kernel<1><<<gg, 256, 0, stream>>>(vx, wvb, bv, vt, 8192, 1024, 1024, 1.0f);
  attn_kernel<<<dim3(64, 16), 256, 0, stream>>>(qp, kp, vt, msk, ao);
  gemm_bt_kernel<2><<<gg, 256, 0, stream>>>(ao, wob, bo, d_out, 8192, 1024, 1024, 1.0f);
}

// Round 4
// 478.870 us; speedup vs baseline: 1.0860x; 1.0860x over previous
//
#include <hip/hip_runtime.h>
#include <hip/hip_bf16.h>

typedef __bf16 bf16;
typedef bf16 bf16x2 __attribute__((ext_vector_type(2)));
typedef bf16 bf16x4 __attribute__((ext_vector_type(4)));
typedef bf16 bf16x8 __attribute__((ext_vector_type(8)));
typedef float f32x4 __attribute__((ext_vector_type(4)));
typedef float f32x16 __attribute__((ext_vector_type(16)));

#define MFMA16(A,B,C) __builtin_amdgcn_mfma_f32_16x16x32_bf16(A,B,C,0,0,0)
#define MFMA32(A,B,C) __builtin_amdgcn_mfma_f32_32x32x16_bf16(A,B,C,0,0,0)

__device__ __forceinline__ void gld_lds16(const void* g, void* l) {
  __builtin_amdgcn_global_load_lds(
      (const __attribute__((address_space(1))) void*)g,
      (__attribute__((address_space(3))) void*)l, 16, 0, 0);
}

// ---------------- fp32 -> bf16 casts (fused launches) ----------------
__global__ void cast3_kernel(const float* __restrict__ s0, const float* __restrict__ s1,
                             const float* __restrict__ s2,
                             bf16* __restrict__ d0, bf16* __restrict__ d1, bf16* __restrict__ d2) {
  const int which = blockIdx.x >> 13;          // 8192 blocks per tensor
  const int i = (blockIdx.x & 8191) * 256 + threadIdx.x;   // float4 index
  const float* s = which == 0 ? s0 : which == 1 ? s1 : s2;
  bf16* d = which == 0 ? d0 : which == 1 ? d1 : d2;
  float4 v = ((const float4*)s)[i];
  bf16x4 o;
  o[0] = (bf16)v.x; o[1] = (bf16)v.y; o[2] = (bf16)v.z; o[3] = (bf16)v.w;
  *(bf16x4*)(d + (size_t)i * 4) = o;
}

__global__ void cast4_kernel(const float* __restrict__ s0, const float* __restrict__ s1,
                             const float* __restrict__ s2, const float* __restrict__ s3,
                             bf16* __restrict__ d0, bf16* __restrict__ d1,
                             bf16* __restrict__ d2, bf16* __restrict__ d3) {
  const int which = blockIdx.x >> 10;          // 1024 blocks per tensor
  const int i = (blockIdx.x & 1023) * 256 + threadIdx.x;
  const float* s = which == 0 ? s0 : which == 1 ? s1 : which == 2 ? s2 : s3;
  bf16* d = which == 0 ? d0 : which == 1 ? d1 : which == 2 ? d2 : d3;
  float4 v = ((const float4*)s)[i];
  bf16x4 o;
  o[0] = (bf16)v.x; o[1] = (bf16)v.y; o[2] = (bf16)v.z; o[3] = (bf16)v.w;
  *(bf16x4*)(d + (size_t)i * 4) = o;
}

// ---------------- GEMM  C = A * B^T  (+bias)*scale ----------------
// A: MxK bf16 row-major, Bm: NxK bf16 row-major (i.e. B-transposed storage).
// OUT_MODE 0: bf16 [M][N];  1: bf16 V^T layout vt[(b*1024+e)][2048]+s;  2: f32 [M][N]
template<int OUT_MODE>
__global__ __launch_bounds__(256) void gemm_bt_kernel(
    const bf16* __restrict__ A, const bf16* __restrict__ Bm,
    const float* __restrict__ bias, void* __restrict__ Cout,
    int M, int N, int K, float scale)
{
  __shared__ bf16 sA[2][128 * 32];
  __shared__ bf16 sB[2][128 * 32];
  const int t = threadIdx.x;
  const int lane = t & 63, w = t >> 6;
  const int wr = w >> 1, wc = w & 1;
  const int g = lane >> 4, c = lane & 15;
  const int bm = blockIdx.y, bn = blockIdx.x;

  f32x4 acc[4][4] = {};

  const int NT = K >> 5;
  const int arow = t >> 2;
  const int acol = (t & 3) * 8;
  const bf16* aBase = A + (size_t)(bm * 128) * K;
  const bf16* bBase = Bm + (size_t)(bn * 128) * K;

  auto stage = [&](int buf, int kt) {
    const int k0 = kt * 32;
#pragma unroll
    for (int i = 0; i < 2; ++i) {
      const int row = arow + i * 64;
      gld_lds16(aBase + (size_t)row * K + k0 + acol, &sA[buf][(i * 256 + t) * 8]);
      gld_lds16(bBase + (size_t)row * K + k0 + acol, &sB[buf][(i * 256 + t) * 8]);
    }
  };

  stage(0, 0);
  __syncthreads();
  int cur = 0;
  for (int kt = 0; kt < NT; ++kt) {
    if (kt + 1 < NT) stage(cur ^ 1, kt + 1);
    bf16x8 af[4], bfr[4];
#pragma unroll
    for (int m = 0; m < 4; ++m)
      af[m] = *(const bf16x8*)&sA[cur][(wr * 64 + m * 16 + c) * 32 + g * 8];
#pragma unroll
    for (int n = 0; n < 4; ++n)
      bfr[n] = *(const bf16x8*)&sB[cur][(wc * 64 + n * 16 + c) * 32 + g * 8];
    __builtin_amdgcn_s_setprio(1);
#pragma unroll
    for (int m = 0; m < 4; ++m)
#pragma unroll
      for (int n = 0; n < 4; ++n)
        acc[m][n] = MFMA16(af[m], bfr[n], acc[m][n]);
    __builtin_amdgcn_s_setprio(0);
    __syncthreads();
    cur ^= 1;
  }

#pragma unroll
  for (int n = 0; n < 4; ++n) {
    const int col = bn * 128 + wc * 64 + n * 16 + c;
    const float bv = bias[col];
#pragma unroll
    for (int m = 0; m < 4; ++m) {
#pragma unroll
      for (int r = 0; r < 4; ++r) {
        const int row = bm * 128 + wr * 64 + m * 16 + g * 4 + r;
        const float val = (acc[m][n][r] + bv) * scale;
        if (OUT_MODE == 0) {
          ((bf16*)Cout)[(size_t)row * N + col] = (bf16)val;
        } else if (OUT_MODE == 1) {
          const int bb = row >> 11, s = row & 2047;
          ((bf16*)Cout)[((size_t)(bb * 1024 + col)) * 2048 + s] = (bf16)val;
        } else {
          ((float*)Cout)[(size_t)row * N + col] = val;
        }
      }
    }
  }
}

// ---------------- flash attention (swapped-operand 32x32x16) ----------------
// Qp: [B*S][D] bf16, pre-scaled by log2(e)/8. Kp: [B*S][D] bf16.
// Vt: [(b*H+h)*DK + dk][S] bf16 (V^T). Out: [B*S][D] bf16.
// Block: 256 thr (4 waves). Each wave owns 32 q-rows; KBLK=64 per iteration.
// S^T = mfma(K,Q): lane holds S[k = kf*32+crow(r,hi)][q = q0w + (lane&31)].
// Softmax is lane-local over 32 values + one shfl_xor(32); m/l are scalars.
// P goes through per-wave LDS [32][72]; PV computes O^T = mfma(V^T, P^T).
__global__ __launch_bounds__(256) void attn_kernel(
    const bf16* __restrict__ Qp, const bf16* __restrict__ Kp, const bf16* __restrict__ Vt,
    const int* __restrict__ mask, bf16* __restrict__ Out)
{
  __shared__ bf16 sK[2][64 * 64];
  __shared__ bf16 sV[2][64 * 64];
  __shared__ bf16 sP[4][32 * 72];   // per-wave P [q][k], stride 72 (rows 16B-aligned, 2-way banks)

  const int bh = blockIdx.x;
  const int b = bh >> 4, h = bh & 15;
  const int t = threadIdx.x, lane = t & 63, w = t >> 6;
  const int q32 = lane & 31, hi = lane >> 5;
  const int q0 = blockIdx.y * 128 + w * 32;

  const char* kBase = (const char*)(Kp + (size_t)(b * 2048) * 1024 + h * 64);
  const char* vBase = (const char*)(Vt + (size_t)(bh * 64) * 2048);

  auto stageKV = [&](int buf, int kt) {
#pragma unroll
    for (int i = 0; i < 2; ++i) {
      const int idx = i * 256 + t;
      const int row = idx >> 3;                          // 0..63
      const int cb = ((t & 7) * 16) ^ ((row & 7) << 4);  // swizzled source byte
      gld_lds16(kBase + (size_t)(kt * 64 + row) * 2048 + cb, (char*)sK[buf] + idx * 16);
      gld_lds16(vBase + (size_t)row * 4096 + kt * 128 + cb, (char*)sV[buf] + idx * 16);
    }
  };

  // Q as B-fragment: col=q32, k = ks*16 + hi*8 + j  (dk dimension)
  bf16x8 qf[4];
  const bf16* qrow = Qp + (size_t)(b * 2048 + q0 + q32) * 1024 + h * 64;
#pragma unroll
  for (int ks = 0; ks < 4; ++ks)
    qf[ks] = *(const bf16x8*)&qrow[ks * 16 + hi * 8];

  float mrun = -1e30f, lrun = 0.f;
  f32x16 aco[2] = {};   // O^T frags: aco[dkf]: O[q=q32][dk = dkf*32 + crow(r,hi)]

  const int* mrow = mask + b * 2048;
  bf16* pr = &sP[w][q32 * 72];

  stageKV(0, 0);
  __syncthreads();
  int cur = 0;
  for (int kt = 0; kt < 32; ++kt) {
    if (kt + 1 < 32) stageKV(cur ^ 1, kt + 1);

    // ---- S^T = K Q^T : st[kf] covers keys kf*32..kf*32+31 ----
    f32x16 st[2] = {};
#pragma unroll
    for (int ks = 0; ks < 4; ++ks) {
      bf16x8 k0f, k1f;
      {
        const int row = q32;
        const int byt = (row * 128 + ks * 32 + hi * 16) ^ ((row & 7) << 4);
        k0f = *(const bf16x8*)((const char*)sK[cur] + byt);
      }
      {
        const int row = 32 + q32;
        const int byt = (row * 128 + ks * 32 + hi * 16) ^ ((row & 7) << 4);
        k1f = *(const bf16x8*)((const char*)sK[cur] + byt);
      }
      __builtin_amdgcn_s_setprio(1);
      st[0] = MFMA32(k0f, qf[ks], st[0]);
      st[1] = MFMA32(k1f, qf[ks], st[1]);
      __builtin_amdgcn_s_setprio(0);
    }

    // ---- mask: k for st[kf][r] = kf*32 + (r&3) + 8*(r>>2) + 4*hi ----
#pragma unroll
    for (int kf = 0; kf < 2; ++kf) {
#pragma unroll
      for (int q4 = 0; q4 < 4; ++q4) {
        const int4 mm = *(const int4*)&mrow[kt * 64 + kf * 32 + q4 * 8 + hi * 4];
        const int mv[4] = {mm.x, mm.y, mm.z, mm.w};
#pragma unroll
        for (int r4 = 0; r4 < 4; ++r4)
          st[kf][q4 * 4 + r4] += (mv[r4] == 0) ? -1e9f : 0.0f;
      }
    }

    // ---- online softmax: lane-local + one cross-half shfl ----
    float tmax = -1e30f;
#pragma unroll
    for (int i = 0; i < 16; ++i)
      tmax = fmaxf(tmax, fmaxf(st[0][i], st[1][i]));
    tmax = fmaxf(tmax, __shfl_xor(tmax, 32, 64));
    const float mnew = fmaxf(mrun, tmax);
    const float sc = exp2f(mrun - mnew);
    mrun = mnew;
    float rs = 0.f;
#pragma unroll
    for (int kf = 0; kf < 2; ++kf)
#pragma unroll
      for (int i = 0; i < 16; ++i) {
        const float p = exp2f(st[kf][i] - mnew);
        st[kf][i] = p;
        rs += p;
      }
    rs += __shfl_xor(rs, 32, 64);
    lrun = lrun * sc + rs;
    aco[0] *= sc;
    aco[1] *= sc;

    // ---- P -> per-wave LDS [q][k], paired b32 writes (k-pairs are reg-consecutive) ----
#pragma unroll
    for (int kf = 0; kf < 2; ++kf)
#pragma unroll
      for (int j = 0; j < 8; ++j) {
        const int k = kf * 32 + (j >> 1) * 8 + hi * 4 + (j & 1) * 2;
        bf16x2 pv;
        pv[0] = (bf16)st[kf][2 * j];
        pv[1] = (bf16)st[kf][2 * j + 1];
        *(bf16x2*)&pr[k] = pv;
      }

    // ---- O^T += V^T P^T ----
    bf16x8 pa[4];
#pragma unroll
    for (int kk = 0; kk < 4; ++kk)
      pa[kk] = *(const bf16x8*)&sP[w][q32 * 72 + kk * 16 + hi * 8];
#pragma unroll
    for (int kk = 0; kk < 4; ++kk) {
      bf16x8 vb0, vb1;
      {
        const int row = q32;       // dk 0..31
        const int byt = (row * 128 + kk * 32 + hi * 16) ^ ((row & 7) << 4);
        vb0 = *(const bf16x8*)((const char*)sV[cur] + byt);
      }
      {
        const int row = 32 + q32;  // dk 32..63
        const int byt = (row * 128 + kk * 32 + hi * 16) ^ ((row & 7) << 4);
        vb1 = *(const bf16x8*)((const char*)sV[cur] + byt);
      }
      __builtin_amdgcn_s_setprio(1);
      aco[0] = MFMA32(vb0, pa[kk], aco[0]);
      aco[1] = MFMA32(vb1, pa[kk], aco[1]);
      __builtin_amdgcn_s_setprio(0);
    }

    __syncthreads();
    cur ^= 1;
  }

  // ---- epilogue: lane owns row q = q0+q32, dk = dkf*32 + q4*8 + hi*4 + r4 ----
  const float inv = 1.0f / lrun;
  bf16* orow = Out + (size_t)(b * 2048 + q0 + q32) * 1024 + h * 64;
#pragma unroll
  for (int dkf = 0; dkf < 2; ++dkf)
#pragma unroll
    for (int q4 = 0; q4 < 4; ++q4) {
      bf16x4 o;
#pragma unroll
      for (int r4 = 0; r4 < 4; ++r4)
        o[r4] = (bf16)(aco[dkf][q4 * 4 + r4] * inv);
      *(bf16x4*)&orow[dkf * 32 + q4 * 8 + hi * 4] = o;
    }
}

extern "C" void kernel_launch(void* const* d_in, const int* in_sizes, int n_in,
                              void* d_out, int out_size, void* d_ws, size_t ws_size,
                              hipStream_t stream) {
  const float* q  = (const float*)d_in[0];
  const float* k  = (const float*)d_in[1];
  const float* v  = (const float*)d_in[2];
  const int*  msk = (const int*)d_in[3];
  const float* wq = (const float*)d_in[4];
  const float* bq = (const float*)d_in[5];
  const float* wk = (const float*)d_in[6];
  const float* bk = (const float*)d_in[7];
  const float* wv = (const float*)d_in[8];
  const float* bv = (const float*)d_in[9];
  const float* wo = (const float*)d_in[10];
  const float* bo = (const float*)d_in[11];

  bf16* ws = (bf16*)d_ws;
  const size_t NEL = 8192ull * 1024ull;  // 8M elements
  bf16* qx  = ws;
  bf16* kx  = ws + NEL;
  bf16* vx  = ws + 2 * NEL;
  bf16* wqb = ws + 3 * NEL;
  bf16* wkb = wqb + 1048576;
  bf16* wvb = wkb + 1048576;
  bf16* wob = wvb + 1048576;
  bf16* qp  = wob + 1048576;
  bf16* kp  = qp + NEL;
  bf16* vt  = kp + NEL;
  bf16* ao  = vx;  // vx dead after V projection

  cast3_kernel<<<24576, 256, 0, stream>>>(q, k, v, qx, kx, vx);
  cast4_kernel<<<4096, 256, 0, stream>>>(wq, wk, wv, wo, wqb, wkb, wvb, wob);

  // Q pre-scale folds softmax 1/sqrt(DK) AND log2(e) for exp2-domain softmax.
  const float qscale = 0.125f * 1.44269504088896f;
  dim3 gg(8, 64);
  gemm_bt_kernel<0><<<gg, 256, 0, stream>>>(qx, wqb, bq, qp, 8192, 1024, 1024, qscale);
  gemm_bt_kernel<0><<<gg, 256, 0, stream>>>(kx, wkb, bk, kp, 8192, 1024, 1024, 1.0f);
  gemm_bt_kernel<1><<<gg, 256, 0, stream>>>(vx, wvb, bv, vt, 8192, 1024, 1024, 1.0f);
  attn_kernel<<<dim3(64, 16), 256, 0, stream>>>(qp, kp, vt, msk, ao);
  gemm_bt_kernel<2><<<gg, 256, 0, stream>>>(ao, wob, bo, d_out, 8192, 1024, 1024, 1.0f);
}

// Round 5
// 447.969 us; speedup vs baseline: 1.1610x; 1.0690x over previous
//
#include <hip/hip_runtime.h>
#include <hip/hip_bf16.h>

typedef __bf16 bf16;
typedef bf16 bf16x2 __attribute__((ext_vector_type(2)));
typedef bf16 bf16x4 __attribute__((ext_vector_type(4)));
typedef bf16 bf16x8 __attribute__((ext_vector_type(8)));
typedef float f32x4 __attribute__((ext_vector_type(4)));
typedef float f32x16 __attribute__((ext_vector_type(16)));
typedef unsigned int u32;
typedef u32 u32x4 __attribute__((ext_vector_type(4)));

#define MFMA16(A,B,C) __builtin_amdgcn_mfma_f32_16x16x32_bf16(A,B,C,0,0,0)
#define MFMA32(A,B,C) __builtin_amdgcn_mfma_f32_32x32x16_bf16(A,B,C,0,0,0)

__device__ __forceinline__ void gld_lds16(const void* g, void* l) {
  __builtin_amdgcn_global_load_lds(
      (const __attribute__((address_space(1))) void*)g,
      (__attribute__((address_space(3))) void*)l, 16, 0, 0);
}

// ---------------- fp32 -> bf16 casts (fused launches) ----------------
__global__ void cast3_kernel(const float* __restrict__ s0, const float* __restrict__ s1,
                             const float* __restrict__ s2,
                             bf16* __restrict__ d0, bf16* __restrict__ d1, bf16* __restrict__ d2) {
  const int which = blockIdx.x >> 13;          // 8192 blocks per tensor
  const int i = (blockIdx.x & 8191) * 256 + threadIdx.x;   // float4 index
  const float* s = which == 0 ? s0 : which == 1 ? s1 : s2;
  bf16* d = which == 0 ? d0 : which == 1 ? d1 : d2;
  float4 v = ((const float4*)s)[i];
  bf16x4 o;
  o[0] = (bf16)v.x; o[1] = (bf16)v.y; o[2] = (bf16)v.z; o[3] = (bf16)v.w;
  *(bf16x4*)(d + (size_t)i * 4) = o;
}

__global__ void cast4_kernel(const float* __restrict__ s0, const float* __restrict__ s1,
                             const float* __restrict__ s2, const float* __restrict__ s3,
                             bf16* __restrict__ d0, bf16* __restrict__ d1,
                             bf16* __restrict__ d2, bf16* __restrict__ d3) {
  const int which = blockIdx.x >> 10;          // 1024 blocks per tensor
  const int i = (blockIdx.x & 1023) * 256 + threadIdx.x;
  const float* s = which == 0 ? s0 : which == 1 ? s1 : which == 2 ? s2 : s3;
  bf16* d = which == 0 ? d0 : which == 1 ? d1 : which == 2 ? d2 : d3;
  float4 v = ((const float4*)s)[i];
  bf16x4 o;
  o[0] = (bf16)v.x; o[1] = (bf16)v.y; o[2] = (bf16)v.z; o[3] = (bf16)v.w;
  *(bf16x4*)(d + (size_t)i * 4) = o;
}

// ---------------- GEMM  C = A * B^T  (+bias)*scale ----------------
// A: MxK bf16 row-major, Bm: NxK bf16 row-major (i.e. B-transposed storage).
// OUT_MODE 0: bf16 [M][N];  1: bf16 V^T layout vt[(b*1024+e)][2048]+s;  2: f32 [M][N]
template<int OUT_MODE>
__global__ __launch_bounds__(256) void gemm_bt_kernel(
    const bf16* __restrict__ A, const bf16* __restrict__ Bm,
    const float* __restrict__ bias, void* __restrict__ Cout,
    int M, int N, int K, float scale)
{
  __shared__ bf16 sA[2][128 * 32];
  __shared__ bf16 sB[2][128 * 32];
  const int t = threadIdx.x;
  const int lane = t & 63, w = t >> 6;
  const int wr = w >> 1, wc = w & 1;
  const int g = lane >> 4, c = lane & 15;
  const int bm = blockIdx.y, bn = blockIdx.x;

  f32x4 acc[4][4] = {};

  const int NT = K >> 5;
  const int arow = t >> 2;
  const int acol = (t & 3) * 8;
  const bf16* aBase = A + (size_t)(bm * 128) * K;
  const bf16* bBase = Bm + (size_t)(bn * 128) * K;

  auto stage = [&](int buf, int kt) {
    const int k0 = kt * 32;
#pragma unroll
    for (int i = 0; i < 2; ++i) {
      const int row = arow + i * 64;
      gld_lds16(aBase + (size_t)row * K + k0 + acol, &sA[buf][(i * 256 + t) * 8]);
      gld_lds16(bBase + (size_t)row * K + k0 + acol, &sB[buf][(i * 256 + t) * 8]);
    }
  };

  stage(0, 0);
  __syncthreads();
  int cur = 0;
  for (int kt = 0; kt < NT; ++kt) {
    if (kt + 1 < NT) stage(cur ^ 1, kt + 1);
    bf16x8 af[4], bfr[4];
#pragma unroll
    for (int m = 0; m < 4; ++m)
      af[m] = *(const bf16x8*)&sA[cur][(wr * 64 + m * 16 + c) * 32 + g * 8];
#pragma unroll
    for (int n = 0; n < 4; ++n)
      bfr[n] = *(const bf16x8*)&sB[cur][(wc * 64 + n * 16 + c) * 32 + g * 8];
    __builtin_amdgcn_s_setprio(1);
#pragma unroll
    for (int m = 0; m < 4; ++m)
#pragma unroll
      for (int n = 0; n < 4; ++n)
        acc[m][n] = MFMA16(af[m], bfr[n], acc[m][n]);
    __builtin_amdgcn_s_setprio(0);
    __syncthreads();
    cur ^= 1;
  }

#pragma unroll
  for (int n = 0; n < 4; ++n) {
    const int col = bn * 128 + wc * 64 + n * 16 + c;
    const float bv = bias[col];
#pragma unroll
    for (int m = 0; m < 4; ++m) {
#pragma unroll
      for (int r = 0; r < 4; ++r) {
        const int row = bm * 128 + wr * 64 + m * 16 + g * 4 + r;
        const float val = (acc[m][n][r] + bv) * scale;
        if (OUT_MODE == 0) {
          ((bf16*)Cout)[(size_t)row * N + col] = (bf16)val;
        } else if (OUT_MODE == 1) {
          const int bb = row >> 11, s = row & 2047;
          ((bf16*)Cout)[((size_t)(bb * 1024 + col)) * 2048 + s] = (bf16)val;
        } else {
          ((float*)Cout)[(size_t)row * N + col] = val;
        }
      }
    }
  }
}

// ---------------- flash attention (swapped-operand 32x32x16, P in-register) ----------------
// Qp: [B*S][D] bf16, pre-scaled by log2(e)/8. Kp: [B*S][D] bf16.
// Vt: [(b*H+h)*DK + dk][S] bf16 (V^T). Out: [B*S][D] bf16.
// Block: 256 thr (4 waves). Each wave owns 32 q-rows; KBLK=64.
// S^T = mfma(K,Q): lane (q32,hi) holds S[k = kf*32 + 8g+4hi+m][q = q0w+q32].
// Softmax lane-local; mask folded into MFMA C-init; defer-max rescale (THR=8*log2e).
// P -> PV A-frags built IN-REGISTER via v_cvt_pk_bf16_f32 + v_permlane32_swap_b32
// (no P LDS round-trip; round-4 counters showed the sP path was 12.58M conflict cyc).
__global__ __launch_bounds__(256) void attn_kernel(
    const bf16* __restrict__ Qp, const bf16* __restrict__ Kp, const bf16* __restrict__ Vt,
    const int* __restrict__ mask, bf16* __restrict__ Out)
{
  __shared__ bf16 sK[2][64 * 64];
  __shared__ bf16 sV[2][64 * 64];

  const int bh = blockIdx.x;
  const int b = bh >> 4, h = bh & 15;
  const int t = threadIdx.x, lane = t & 63, w = t >> 6;
  const int q32 = lane & 31, hi = lane >> 5;
  const int q0 = blockIdx.y * 128 + w * 32;

  const char* kBase = (const char*)(Kp + (size_t)(b * 2048) * 1024 + h * 64);
  const char* vBase = (const char*)(Vt + (size_t)(bh * 64) * 2048);

  auto stageKV = [&](int buf, int kt) {
#pragma unroll
    for (int i = 0; i < 2; ++i) {
      const int idx = i * 256 + t;
      const int row = idx >> 3;                          // 0..63
      const int cb = ((t & 7) * 16) ^ ((row & 7) << 4);  // swizzled source byte
      gld_lds16(kBase + (size_t)(kt * 64 + row) * 2048 + cb, (char*)sK[buf] + idx * 16);
      gld_lds16(vBase + (size_t)row * 4096 + kt * 128 + cb, (char*)sV[buf] + idx * 16);
    }
  };

  // Q as B-fragment: col=q32, k = ks*16 + hi*8 + j  (dk dimension)
  bf16x8 qf[4];
  const bf16* qrow = Qp + (size_t)(b * 2048 + q0 + q32) * 1024 + h * 64;
#pragma unroll
  for (int ks = 0; ks < 4; ++ks)
    qf[ks] = *(const bf16x8*)&qrow[ks * 16 + hi * 8];

  float mrun = -1e30f, lrun = 0.f;
  f32x16 aco[2] = {};   // O^T frags: aco[dkf]: O[q=q32][dk = dkf*32 + crow(r,hi)]

  const int* mrow = mask + b * 2048;

  stageKV(0, 0);
  __syncthreads();
  int cur = 0;
  for (int kt = 0; kt < 32; ++kt) {
    if (kt + 1 < 32) stageKV(cur ^ 1, kt + 1);

    // ---- init S^T from mask (replaces zero-init AND the post-MFMA mask add) ----
    // st[kf][q4*4+r4] is key k = kf*32 + q4*8 + hi*4 + r4.
    f32x16 st[2];
#pragma unroll
    for (int kf = 0; kf < 2; ++kf)
#pragma unroll
      for (int q4 = 0; q4 < 4; ++q4) {
        const int4 mm = *(const int4*)&mrow[kt * 64 + kf * 32 + q4 * 8 + hi * 4];
        st[kf][q4 * 4 + 0] = mm.x ? 0.0f : -1e9f;
        st[kf][q4 * 4 + 1] = mm.y ? 0.0f : -1e9f;
        st[kf][q4 * 4 + 2] = mm.z ? 0.0f : -1e9f;
        st[kf][q4 * 4 + 3] = mm.w ? 0.0f : -1e9f;
      }

    // ---- S^T += K Q^T ----
#pragma unroll
    for (int ks = 0; ks < 4; ++ks) {
      bf16x8 k0f, k1f;
      {
        const int row = q32;
        const int byt = (row * 128 + ks * 32 + hi * 16) ^ ((row & 7) << 4);
        k0f = *(const bf16x8*)((const char*)sK[cur] + byt);
      }
      {
        const int row = 32 + q32;
        const int byt = (row * 128 + ks * 32 + hi * 16) ^ ((row & 7) << 4);
        k1f = *(const bf16x8*)((const char*)sK[cur] + byt);
      }
      __builtin_amdgcn_s_setprio(1);
      st[0] = MFMA32(k0f, qf[ks], st[0]);
      st[1] = MFMA32(k1f, qf[ks], st[1]);
      __builtin_amdgcn_s_setprio(0);
    }

    // ---- online softmax: tree max, defer-max rescale, tree sum ----
    float t0 = fmaxf(st[0][0], st[0][1]), t1 = fmaxf(st[0][2], st[0][3]);
    float t2 = fmaxf(st[1][0], st[1][1]), t3 = fmaxf(st[1][2], st[1][3]);
#pragma unroll
    for (int i = 4; i < 16; i += 4) {
      t0 = fmaxf(t0, fmaxf(st[0][i], st[0][i + 1]));
      t1 = fmaxf(t1, fmaxf(st[0][i + 2], st[0][i + 3]));
      t2 = fmaxf(t2, fmaxf(st[1][i], st[1][i + 1]));
      t3 = fmaxf(t3, fmaxf(st[1][i + 2], st[1][i + 3]));
    }
    float tmax = fmaxf(fmaxf(t0, t1), fmaxf(t2, t3));
    tmax = fmaxf(tmax, __shfl_xor(tmax, 32, 64));
    if (!__all(tmax <= mrun + 11.5f)) {   // defer-max: THR = 8*log2(e)
      const float mnew = fmaxf(mrun, tmax);
      const float sc = exp2f(mrun - mnew);
      mrun = mnew;
      lrun *= sc;
      aco[0] *= sc;
      aco[1] *= sc;
    }
    float rs0 = 0.f, rs1 = 0.f, rs2 = 0.f, rs3 = 0.f;
#pragma unroll
    for (int i = 0; i < 16; i += 4) {
      float p00 = exp2f(st[0][i] - mrun),     p01 = exp2f(st[0][i + 1] - mrun);
      float p02 = exp2f(st[0][i + 2] - mrun), p03 = exp2f(st[0][i + 3] - mrun);
      float p10 = exp2f(st[1][i] - mrun),     p11 = exp2f(st[1][i + 1] - mrun);
      float p12 = exp2f(st[1][i + 2] - mrun), p13 = exp2f(st[1][i + 3] - mrun);
      st[0][i] = p00; st[0][i + 1] = p01; st[0][i + 2] = p02; st[0][i + 3] = p03;
      st[1][i] = p10; st[1][i + 1] = p11; st[1][i + 2] = p12; st[1][i + 3] = p13;
      rs0 += p00 + p01; rs1 += p02 + p03;
      rs2 += p10 + p11; rs3 += p12 + p13;
    }
    float rs = (rs0 + rs1) + (rs2 + rs3);
    rs += __shfl_xor(rs, 32, 64);
    lrun += rs;

    // ---- P -> PV A-frags fully in-register (T12): cvt_pk pairs then permlane32_swap.
    // Lane (q32,hi) holds k_local = 8g+4hi+{0..3} at st[kf][4g+m]; PV needs
    // k = kk*16 + hi*8 + {0..7}. pk(u[g][0])=k(8g+4hi+0,1), pk(u[g][1])=k(+2,3).
    // permlane32_swap(x,y): x'=[x_lo,y_lo], y'=[x_hi,y_hi]  =>
    //   swap(u[g][j], u[g+1][j]) yields dword j (lo lanes k(8g..), hi lanes k(8g+8..))
    //   and dword j+2 (lo k(8g+4..), hi k(8g+12..)).
    bf16x8 pa[4];
#pragma unroll
    for (int kf = 0; kf < 2; ++kf) {
      u32 u[4][2];
#pragma unroll
      for (int g2 = 0; g2 < 4; ++g2) {
        asm("v_cvt_pk_bf16_f32 %0, %1, %2"
            : "=v"(u[g2][0]) : "v"(st[kf][4 * g2 + 0]), "v"(st[kf][4 * g2 + 1]));
        asm("v_cvt_pk_bf16_f32 %0, %1, %2"
            : "=v"(u[g2][1]) : "v"(st[kf][4 * g2 + 2]), "v"(st[kf][4 * g2 + 3]));
      }
      u32 d0 = u[0][0], d2 = u[1][0];
      asm("v_permlane32_swap_b32 %0, %1" : "+v"(d0), "+v"(d2));
      u32 d1 = u[0][1], d3 = u[1][1];
      asm("v_permlane32_swap_b32 %0, %1" : "+v"(d1), "+v"(d3));
      u32x4 ud = {d0, d1, d2, d3};
      pa[2 * kf] = __builtin_bit_cast(bf16x8, ud);
      u32 e0 = u[2][0], e2 = u[3][0];
      asm("v_permlane32_swap_b32 %0, %1" : "+v"(e0), "+v"(e2));
      u32 e1 = u[2][1], e3 = u[3][1];
      asm("v_permlane32_swap_b32 %0, %1" : "+v"(e1), "+v"(e3));
      u32x4 ue = {e0, e1, e2, e3};
      pa[2 * kf + 1] = __builtin_bit_cast(bf16x8, ue);
    }

    // ---- O^T += V^T P^T ----
#pragma unroll
    for (int kk = 0; kk < 4; ++kk) {
      bf16x8 vb0, vb1;
      {
        const int row = q32;       // dk 0..31
        const int byt = (row * 128 + kk * 32 + hi * 16) ^ ((row & 7) << 4);
        vb0 = *(const bf16x8*)((const char*)sV[cur] + byt);
      }
      {
        const int row = 32 + q32;  // dk 32..63
        const int byt = (row * 128 + kk * 32 + hi * 16) ^ ((row & 7) << 4);
        vb1 = *(const bf16x8*)((const char*)sV[cur] + byt);
      }
      __builtin_amdgcn_s_setprio(1);
      aco[0] = MFMA32(vb0, pa[kk], aco[0]);
      aco[1] = MFMA32(vb1, pa[kk], aco[1]);
      __builtin_amdgcn_s_setprio(0);
    }

    __syncthreads();
    cur ^= 1;
  }

  // ---- epilogue: lane owns row q = q0+q32, dk = dkf*32 + q4*8 + hi*4 + r4 ----
  const float inv = 1.0f / lrun;
  bf16* orow = Out + (size_t)(b * 2048 + q0 + q32) * 1024 + h * 64;
#pragma unroll
  for (int dkf = 0; dkf < 2; ++dkf)
#pragma unroll
    for (int q4 = 0; q4 < 4; ++q4) {
      bf16x4 o;
#pragma unroll
      for (int r4 = 0; r4 < 4; ++r4)
        o[r4] = (bf16)(aco[dkf][q4 * 4 + r4] * inv);
      *(bf16x4*)&orow[dkf * 32 + q4 * 8 + hi * 4] = o;
    }
}

extern "C" void kernel_launch(void* const* d_in, const int* in_sizes, int n_in,
                              void* d_out, int out_size, void* d_ws, size_t ws_size,
                              hipStream_t stream) {
  const float* q  = (const float*)d_in[0];
  const float* k  = (const float*)d_in[1];
  const float* v  = (const float*)d_in[2];
  const int*  msk = (const int*)d_in[3];
  const float* wq = (const float*)d_in[4];
  const float* bq = (const float*)d_in[5];
  const float* wk = (const float*)d_in[6];
  const float* bk = (const float*)d_in[7];
  const float* wv = (const float*)d_in[8];
  const float* bv = (const float*)d_in[9];
  const float* wo = (const float*)d_in[10];
  const float* bo = (const float*)d_in[11];

  bf16* ws = (bf16*)d_ws;
  const size_t NEL = 8192ull * 1024ull;  // 8M elements
  bf16* qx  = ws;
  bf16* kx  = ws + NEL;
  bf16* vx  = ws + 2 * NEL;
  bf16* wqb = ws + 3 * NEL;
  bf16* wkb = wqb + 1048576;
  bf16* wvb = wkb + 1048576;
  bf16* wob = wvb + 1048576;
  bf16* qp  = wob + 1048576;
  bf16* kp  = qp + NEL;
  bf16* vt  = kp + NEL;
  bf16* ao  = vx;  // vx dead after V projection

  cast3_kernel<<<24576, 256, 0, stream>>>(q, k, v, qx, kx, vx);
  cast4_kernel<<<4096, 256, 0, stream>>>(wq, wk, wv, wo, wqb, wkb, wvb, wob);

  // Q pre-scale folds softmax 1/sqrt(DK) AND log2(e) for exp2-domain softmax.
  const float qscale = 0.125f * 1.44269504088896f;
  dim3 gg(8, 64);
  gemm_bt_kernel<0><<<gg, 256, 0, stream>>>(qx, wqb, bq, qp, 8192, 1024, 1024, qscale);
  gemm_bt_kernel<0><<<gg, 256, 0, stream>>>(kx, wkb, bk, kp, 8192, 1024, 1024, 1.0f);
  gemm_bt_kernel<1><<<gg, 256, 0, stream>>>(vx, wvb, bv, vt, 8192, 1024, 1024, 1.0f);
  attn_kernel<<<dim3(64, 16), 256, 0, stream>>>(qp, kp, vt, msk, ao);
  gemm_bt_kernel<2><<<gg, 256, 0, stream>>>(ao, wob, bo, d_out, 8192, 1024, 1024, 1.0f);
}